// Round 6
// baseline (195.393 us; speedup 1.0000x reference)
//
#include <hip/hip_runtime.h>

// Problem constants (from reference)
#define NB 4
#define NN 20000
#define NE 320000
#define HH 128

#define HBLK 64     // histogram blocks (each holds a full 80 KB LDS histogram)
#define HTHR 1024   // threads per histogram block
#define CHUNKS 256  // node chunks for the weighted-sum kernel
#define WTHR 512    // threads per wsum block (16 node-groups x 32 lanes)

// ws layout (floats):
//   pdeg   [HBLK][NN]          per-block degree partials
//   dinv   [NN]                rsqrt(deg+1)
//   ps     [HBLK][NN]          per-block s partials
//   w      [NN]                final node weight
//   partial[CHUNKS][NB][HH]    wsum partials
//   counter (1 int)            completion counter for last-block MLP
#define OFF_PDEG    0
#define OFF_DINV    (HBLK * NN)
#define OFF_PS      (OFF_DINV + NN)
#define OFF_W       (OFF_PS + HBLK * NN)
#define OFF_PARTIAL (OFF_W + NN)
#define OFF_COUNTER (OFF_PARTIAL + CHUNKS * NB * HH)

// --- K1: per-block LDS degree histogram (NO global atomics) ---
__global__ void __launch_bounds__(HTHR) deg_hist_kernel(
        const int* __restrict__ dst, float* __restrict__ pdeg) {
    __shared__ float hist[NN];   // 80 KB
    const int t = threadIdx.x, bk = blockIdx.x;
    for (int i = t; i < NN; i += HTHR) hist[i] = 0.0f;
    __syncthreads();
    for (int e = bk * HTHR + t; e < NE; e += HBLK * HTHR)
        atomicAdd(&hist[dst[e]], 1.0f);          // LDS atomic (ds_add_f32)
    __syncthreads();
    float* out = pdeg + (size_t)bk * NN;
    for (int i = t; i < NN; i += HTHR) out[i] = hist[i];  // coalesced dump
}

// --- K2: dinv[n] = rsqrt(1 + sum_c pdeg[c][n]) ---
__global__ void reduce_deg_kernel(const float* __restrict__ pdeg,
                                  float* __restrict__ dinv) {
    const int n = blockIdx.x * 256 + threadIdx.x;
    if (n >= NN) return;
    float acc = 1.0f;  // self-loop
    #pragma unroll 8
    for (int c = 0; c < HBLK; ++c) acc += pdeg[(size_t)c * NN + n];
    dinv[n] = rsqrtf(acc);
}

// --- K3: per-block LDS s histogram: s[src] += dinv[dst] ---
__global__ void __launch_bounds__(HTHR) s_hist_kernel(
        const int* __restrict__ src, const int* __restrict__ dst,
        const float* __restrict__ dinv, float* __restrict__ ps) {
    __shared__ float hist[NN];   // 80 KB
    const int t = threadIdx.x, bk = blockIdx.x;
    for (int i = t; i < NN; i += HTHR) hist[i] = 0.0f;
    __syncthreads();
    for (int e = bk * HTHR + t; e < NE; e += HBLK * HTHR)
        atomicAdd(&hist[src[e]], dinv[dst[e]]);  // L2-resident gather + LDS atomic
    __syncthreads();
    float* out = ps + (size_t)bk * NN;
    for (int i = t; i < NN; i += HTHR) out[i] = hist[i];
}

// --- K4: w[n] = dinv[n]*(dinv[n] + sum_c ps[c][n]); also reset counter ---
__global__ void reduce_w_kernel(const float* __restrict__ ps,
                                const float* __restrict__ dinv,
                                float* __restrict__ w, int* __restrict__ counter) {
    if (blockIdx.x == 0 && threadIdx.x == 0) *counter = 0;  // runs before K5 (stream order)
    const int n = blockIdx.x * 256 + threadIdx.x;
    if (n >= NN) return;
    float acc = 0.0f;
    #pragma unroll 8
    for (int c = 0; c < HBLK; ++c) acc += ps[(size_t)c * NN + n];
    const float di = dinv[n];
    w[n] = di * (di + acc);
}

// --- K5: weighted feature sum -> partials; last block reduces + runs MLP ---
// grid (CHUNKS, NB), 512 threads = 16 node-groups x 32 lanes.
// q<16 lanes cover feat_a[n, q*4..q*4+3], q>=16 cover feat_b.
__global__ void __launch_bounds__(WTHR) wsum_mlp_kernel(
        const float* __restrict__ fa, const float* __restrict__ fb,
        const float* __restrict__ w,
        const float* __restrict__ Wg, const float* __restrict__ bg,
        const float* __restrict__ W1, const float* __restrict__ b1,
        const float* __restrict__ W2, const float* __restrict__ b2,
        float* __restrict__ partial, int* __restrict__ counter,
        float* __restrict__ out) {
    const int t = threadIdx.x;
    const int c = blockIdx.x, b = blockIdx.y;
    const int per = (NN + CHUNKS - 1) / CHUNKS;   // 79
    const int n0 = c * per;
    const int n1 = min(NN, n0 + per);
    const int g = t >> 5;        // node subgroup 0..15
    const int q = t & 31;
    const float* base = (q < 16)
        ? (fa + (size_t)b * NN * 64 + (size_t)q * 4)
        : (fb + (size_t)b * NN * 64 + (size_t)(q - 16) * 4);

    float4 acc = make_float4(0.f, 0.f, 0.f, 0.f);
    for (int n = n0 + g; n < n1; n += 16) {
        float wn = w[n];
        float4 x = *reinterpret_cast<const float4*>(base + (size_t)n * 64);
        acc.x += wn * x.x; acc.y += wn * x.y; acc.z += wn * x.z; acc.w += wn * x.w;
    }

    __shared__ float4 smem[WTHR];
    smem[t] = acc;
    __syncthreads();
    if (t < 32) {
        float4 r = smem[t];
        #pragma unroll
        for (int gg = 1; gg < 16; ++gg) {
            float4 o = smem[gg * 32 + t];
            r.x += o.x; r.y += o.y; r.z += o.z; r.w += o.w;
        }
        const int k = (t < 16) ? t * 4 : 64 + (t - 16) * 4;
        float* p = partial + ((size_t)c * NB + b) * HH + k;
        p[0] = r.x; p[1] = r.y; p[2] = r.z; p[3] = r.w;
    }
    __syncthreads();

    // completion detection (rocPRIM-style last-block pattern)
    __threadfence();             // flush this block's partial stores device-wide
    __shared__ int lastflag;
    if (t == 0) {
        int old = atomicAdd(counter, 1);
        lastflag = (old == CHUNKS * NB - 1);
    }
    __syncthreads();
    if (!lastflag) return;
    __threadfence();             // acquire side before reading others' partials

    // ---- last block: reduce partials and run MLP for all 4 batches ----
    __shared__ float xs[NB][HH];
    __shared__ float ys[NB][HH];
    __shared__ float red[NB][HH];
    const int bb = t >> 7;           // 0..3
    const int kk = t & (HH - 1);     // 0..127

    float vsum = 0.0f;
    #pragma unroll 8
    for (int cc = 0; cc < CHUNKS; ++cc)
        vsum += partial[((size_t)cc * NB + bb) * HH + kk];
    xs[bb][kk] = vsum * (1.0f / NN);
    __syncthreads();

    // layer 1: pooled = xs @ Wg + bg
    float a1 = bg[kk];
    #pragma unroll 8
    for (int j = 0; j < HH; ++j) a1 += xs[bb][j] * Wg[j * HH + kk];
    ys[bb][kk] = a1;
    __syncthreads();

    // layer 2: hid = relu(ys @ W1 + b1), fold W2 scale
    float a2 = b1[kk];
    #pragma unroll 8
    for (int j = 0; j < HH; ++j) a2 += ys[bb][j] * W1[j * HH + kk];
    a2 = fmaxf(a2, 0.0f);
    red[bb][kk] = a2 * W2[kk];
    __syncthreads();

    // tree-reduce 128 -> 1 per batch
    #pragma unroll
    for (int off = HH / 2; off > 0; off >>= 1) {
        if (kk < off) red[bb][kk] += red[bb][kk + off];
        __syncthreads();
    }
    if (kk == 0) out[bb] = red[bb][0] + b2[0];
}

extern "C" void kernel_launch(void* const* d_in, const int* in_sizes, int n_in,
                              void* d_out, int out_size, void* d_ws, size_t ws_size,
                              hipStream_t stream) {
    const float* fa = (const float*)d_in[0];   // [B,N,64]
    const float* fb = (const float*)d_in[1];   // [B,N,64]
    const int*   ei = (const int*)d_in[2];     // [2,E]
    const float* Wg = (const float*)d_in[3];   // [H,H]
    const float* bg = (const float*)d_in[4];   // [H]
    const float* W1 = (const float*)d_in[5];   // [H,H]
    const float* b1 = (const float*)d_in[6];   // [H]
    const float* W2 = (const float*)d_in[7];   // [H,1]
    const float* b2 = (const float*)d_in[8];   // [1]
    float* out = (float*)d_out;

    const int* src = ei;
    const int* dst = ei + NE;

    float* ws   = (float*)d_ws;
    float* pdeg = ws + OFF_PDEG;
    float* dinv = ws + OFF_DINV;
    float* ps   = ws + OFF_PS;
    float* w    = ws + OFF_W;
    float* prt  = ws + OFF_PARTIAL;
    int* counter = (int*)(ws + OFF_COUNTER);

    deg_hist_kernel<<<HBLK, HTHR, 0, stream>>>(dst, pdeg);

    const int rb = (NN + 255) / 256;
    reduce_deg_kernel<<<rb, 256, 0, stream>>>(pdeg, dinv);

    s_hist_kernel<<<HBLK, HTHR, 0, stream>>>(src, dst, dinv, ps);

    reduce_w_kernel<<<rb, 256, 0, stream>>>(ps, dinv, w, counter);

    dim3 grid(CHUNKS, NB);
    wsum_mlp_kernel<<<grid, WTHR, 0, stream>>>(fa, fb, w, Wg, bg, W1, b1, W2, b2,
                                               prt, counter, out);
}

// Round 7
// 64.593 us; speedup vs baseline: 3.0250x; 3.0250x over previous
//
#include <hip/hip_runtime.h>

// Problem constants (from reference)
#define NB 4
#define NN 20000
#define NE 320000
#define HH 128

#define HBLK 64     // histogram blocks (each holds a full 80 KB LDS histogram)
#define HTHR 1024   // threads per histogram block
#define CHUNKS 256  // node chunks for the weighted-sum kernel
#define WTHR 512    // threads per wsum block (16 node-groups x 32 lanes)

// ws layout (floats):
//   pdeg   [HBLK][NN]          per-block degree partials
//   dinv   [NN]                rsqrt(deg+1)
//   ps     [HBLK][NN]          per-block s partials
//   w      [NN]                final node weight
//   partial[CHUNKS][NB][HH]    wsum partials
#define OFF_PDEG    0
#define OFF_DINV    (HBLK * NN)
#define OFF_PS      (OFF_DINV + NN)
#define OFF_W       (OFF_PS + HBLK * NN)
#define OFF_PARTIAL (OFF_W + NN)

// --- K1: per-block LDS degree histogram (NO global atomics) ---
__global__ void __launch_bounds__(HTHR) deg_hist_kernel(
        const int* __restrict__ dst, float* __restrict__ pdeg) {
    __shared__ float hist[NN];   // 80 KB
    const int t = threadIdx.x, bk = blockIdx.x;
    for (int i = t; i < NN; i += HTHR) hist[i] = 0.0f;
    __syncthreads();
    for (int e = bk * HTHR + t; e < NE; e += HBLK * HTHR)
        atomicAdd(&hist[dst[e]], 1.0f);          // LDS atomic (ds_add_f32)
    __syncthreads();
    float* out = pdeg + (size_t)bk * NN;
    for (int i = t; i < NN; i += HTHR) out[i] = hist[i];  // coalesced dump
}

// --- K2: dinv[n] = rsqrt(1 + sum_c pdeg[c][n]) ---
__global__ void reduce_deg_kernel(const float* __restrict__ pdeg,
                                  float* __restrict__ dinv) {
    const int n = blockIdx.x * 256 + threadIdx.x;
    if (n >= NN) return;
    float acc = 1.0f;  // self-loop
    #pragma unroll 8
    for (int c = 0; c < HBLK; ++c) acc += pdeg[(size_t)c * NN + n];
    dinv[n] = rsqrtf(acc);
}

// --- K3: per-block LDS s histogram: s[src] += dinv[dst] ---
__global__ void __launch_bounds__(HTHR) s_hist_kernel(
        const int* __restrict__ src, const int* __restrict__ dst,
        const float* __restrict__ dinv, float* __restrict__ ps) {
    __shared__ float hist[NN];   // 80 KB
    const int t = threadIdx.x, bk = blockIdx.x;
    for (int i = t; i < NN; i += HTHR) hist[i] = 0.0f;
    __syncthreads();
    for (int e = bk * HTHR + t; e < NE; e += HBLK * HTHR)
        atomicAdd(&hist[src[e]], dinv[dst[e]]);  // L2-resident gather + LDS atomic
    __syncthreads();
    float* out = ps + (size_t)bk * NN;
    for (int i = t; i < NN; i += HTHR) out[i] = hist[i];
}

// --- K4: w[n] = dinv[n]*(dinv[n] + sum_c ps[c][n]) ---
__global__ void reduce_w_kernel(const float* __restrict__ ps,
                                const float* __restrict__ dinv,
                                float* __restrict__ w) {
    const int n = blockIdx.x * 256 + threadIdx.x;
    if (n >= NN) return;
    float acc = 0.0f;
    #pragma unroll 8
    for (int c = 0; c < HBLK; ++c) acc += ps[(size_t)c * NN + n];
    const float di = dinv[n];
    w[n] = di * (di + acc);
}

// --- K5: weighted feature sum -> per-block partials (no atomics, no fences) ---
// grid (CHUNKS, NB), 512 threads = 16 node-groups x 32 lanes.
// q<16 lanes cover feat_a[n, q*4..q*4+3], q>=16 cover feat_b.
__global__ void __launch_bounds__(WTHR) wsum_kernel(
        const float* __restrict__ fa, const float* __restrict__ fb,
        const float* __restrict__ w, float* __restrict__ partial) {
    const int t = threadIdx.x;
    const int c = blockIdx.x, b = blockIdx.y;
    const int per = (NN + CHUNKS - 1) / CHUNKS;   // 79
    const int n0 = c * per;
    const int n1 = min(NN, n0 + per);
    const int g = t >> 5;        // node subgroup 0..15
    const int q = t & 31;
    const float* base = (q < 16)
        ? (fa + (size_t)b * NN * 64 + (size_t)q * 4)
        : (fb + (size_t)b * NN * 64 + (size_t)(q - 16) * 4);

    float4 acc = make_float4(0.f, 0.f, 0.f, 0.f);
    for (int n = n0 + g; n < n1; n += 16) {
        float wn = w[n];
        float4 x = *reinterpret_cast<const float4*>(base + (size_t)n * 64);
        acc.x += wn * x.x; acc.y += wn * x.y; acc.z += wn * x.z; acc.w += wn * x.w;
    }

    __shared__ float4 smem[WTHR];
    smem[t] = acc;
    __syncthreads();
    if (t < 32) {
        float4 r = smem[t];
        #pragma unroll
        for (int gg = 1; gg < 16; ++gg) {
            float4 o = smem[gg * 32 + t];
            r.x += o.x; r.y += o.y; r.z += o.z; r.w += o.w;
        }
        const int k = (t < 16) ? t * 4 : 64 + (t - 16) * 4;
        float* p = partial + ((size_t)c * NB + b) * HH + k;
        p[0] = r.x; p[1] = r.y; p[2] = r.z; p[3] = r.w;
    }
}

// --- K6: reduce partials + MLP head. One block, B*H = 512 threads. ---
// Thread t owns (b = t>>7, k = t&127).
__global__ void __launch_bounds__(NB * HH) mlp_kernel(
        const float* __restrict__ partial,
        const float* __restrict__ Wg, const float* __restrict__ bg,
        const float* __restrict__ W1, const float* __restrict__ b1,
        const float* __restrict__ W2, const float* __restrict__ b2,
        float* __restrict__ out) {
    __shared__ float xs[NB][HH];
    __shared__ float ys[NB][HH];
    __shared__ float red[NB][HH];
    const int t = threadIdx.x;
    const int bb = t >> 7;           // 0..3
    const int kk = t & (HH - 1);     // 0..127

    float vsum = 0.0f;
    #pragma unroll 8
    for (int cc = 0; cc < CHUNKS; ++cc)
        vsum += partial[((size_t)cc * NB + bb) * HH + kk];
    xs[bb][kk] = vsum * (1.0f / NN);
    __syncthreads();

    // layer 1: pooled = xs @ Wg + bg
    float a1 = bg[kk];
    #pragma unroll 8
    for (int j = 0; j < HH; ++j) a1 += xs[bb][j] * Wg[j * HH + kk];
    ys[bb][kk] = a1;
    __syncthreads();

    // layer 2: hid = relu(ys @ W1 + b1), fold W2 scale
    float a2 = b1[kk];
    #pragma unroll 8
    for (int j = 0; j < HH; ++j) a2 += ys[bb][j] * W1[j * HH + kk];
    a2 = fmaxf(a2, 0.0f);
    red[bb][kk] = a2 * W2[kk];
    __syncthreads();

    // tree-reduce 128 -> 1 per batch
    #pragma unroll
    for (int off = HH / 2; off > 0; off >>= 1) {
        if (kk < off) red[bb][kk] += red[bb][kk + off];
        __syncthreads();
    }
    if (kk == 0) out[bb] = red[bb][0] + b2[0];
}

extern "C" void kernel_launch(void* const* d_in, const int* in_sizes, int n_in,
                              void* d_out, int out_size, void* d_ws, size_t ws_size,
                              hipStream_t stream) {
    const float* fa = (const float*)d_in[0];   // [B,N,64]
    const float* fb = (const float*)d_in[1];   // [B,N,64]
    const int*   ei = (const int*)d_in[2];     // [2,E]
    const float* Wg = (const float*)d_in[3];   // [H,H]
    const float* bg = (const float*)d_in[4];   // [H]
    const float* W1 = (const float*)d_in[5];   // [H,H]
    const float* b1 = (const float*)d_in[6];   // [H]
    const float* W2 = (const float*)d_in[7];   // [H,1]
    const float* b2 = (const float*)d_in[8];   // [1]
    float* out = (float*)d_out;

    const int* src = ei;
    const int* dst = ei + NE;

    float* ws   = (float*)d_ws;
    float* pdeg = ws + OFF_PDEG;
    float* dinv = ws + OFF_DINV;
    float* ps   = ws + OFF_PS;
    float* w    = ws + OFF_W;
    float* prt  = ws + OFF_PARTIAL;

    deg_hist_kernel<<<HBLK, HTHR, 0, stream>>>(dst, pdeg);

    const int rb = (NN + 255) / 256;
    reduce_deg_kernel<<<rb, 256, 0, stream>>>(pdeg, dinv);

    s_hist_kernel<<<HBLK, HTHR, 0, stream>>>(src, dst, dinv, ps);

    reduce_w_kernel<<<rb, 256, 0, stream>>>(ps, dinv, w);

    dim3 grid(CHUNKS, NB);
    wsum_kernel<<<grid, WTHR, 0, stream>>>(fa, fb, w, prt);

    mlp_kernel<<<1, NB * HH, 0, stream>>>(prt, Wg, bg, W1, b1, W2, b2, out);
}